// Round 1
// baseline (131.813 us; speedup 1.0000x reference)
//
#include <hip/hip_runtime.h>

#define NCLASS 16
#define D 128
#define EPSF 1e-6f
#define MF 10.0f

// ws layout (floats): S[NCLASS*D] | Q[NCLASS] | CNT[NCLASS] | sumLoss | sumValid
#define WS_S   0
#define WS_Q   (NCLASS * D)
#define WS_CNT (WS_Q + NCLASS)
#define WS_SUM (WS_CNT + NCLASS)
#define WS_FLOATS (WS_SUM + 2)

// Kernel 1: per-class aggregation. Block = 128 threads (thread = column).
// Each block processes rows r = blockIdx.x, +gridDim.x, ...
// LDS address (c, col) is touched ONLY by thread `col` -> no races, no atomics
// inside the loop. One global atomicAdd fan-in per block at the end.
__global__ void __launch_bounds__(128)
agg_kernel(const float* __restrict__ F, const int* __restrict__ L,
           float* __restrict__ ws, int n) {
    __shared__ float S_lds[NCLASS * D];
    __shared__ float SQ_lds[NCLASS * D];
    __shared__ float cnt_lds[NCLASS];
    const int col = threadIdx.x;  // 0..127
    for (int i = threadIdx.x; i < NCLASS * D; i += blockDim.x) {
        S_lds[i] = 0.f;
        SQ_lds[i] = 0.f;
    }
    if (threadIdx.x < NCLASS) cnt_lds[threadIdx.x] = 0.f;
    __syncthreads();

    for (int r = blockIdx.x; r < n; r += gridDim.x) {
        const int c = L[r];                       // broadcast load
        const float v = F[(size_t)r * D + col];   // fully coalesced
        S_lds[c * D + col] += v;
        SQ_lds[c * D + col] += v * v;
        if (col == 0) cnt_lds[c] += 1.f;
    }
    __syncthreads();

    for (int c = 0; c < NCLASS; ++c)
        atomicAdd(&ws[WS_S + c * D + col], S_lds[c * D + col]);
    if (threadIdx.x < NCLASS) {
        const int c = threadIdx.x;
        float q = 0.f;
        for (int j = 0; j < D; ++j) q += SQ_lds[c * D + j];
        atomicAdd(&ws[WS_Q + c], q);
        atomicAdd(&ws[WS_CNT + c], cnt_lds[c]);
    }
}

// Kernel 2: one wave (64 lanes) per row; float2 loads cover D=128.
// Three wave reductions (sq, dot_same, dot_tot) -> closed-form loss per row.
__global__ void __launch_bounds__(256)
loss_kernel(const float* __restrict__ F, const int* __restrict__ L,
            float* __restrict__ ws, int n) {
    __shared__ float S_lds[NCLASS * D];
    __shared__ float Stot[D];
    __shared__ float Q_lds[NCLASS];
    __shared__ float cnt_lds[NCLASS];
    __shared__ float Qtot_s;

    for (int i = threadIdx.x; i < NCLASS * D; i += blockDim.x)
        S_lds[i] = ws[WS_S + i];
    if (threadIdx.x < NCLASS) {
        Q_lds[threadIdx.x] = ws[WS_Q + threadIdx.x];
        cnt_lds[threadIdx.x] = ws[WS_CNT + threadIdx.x];
    }
    __syncthreads();
    if (threadIdx.x < D) {
        float s = 0.f;
        for (int c = 0; c < NCLASS; ++c) s += S_lds[c * D + threadIdx.x];
        Stot[threadIdx.x] = s;
    }
    if (threadIdx.x == 0) {
        float q = 0.f;
        for (int c = 0; c < NCLASS; ++c) q += Q_lds[c];
        Qtot_s = q;
    }
    __syncthreads();

    const int lane = threadIdx.x & 63;
    const int wave = threadIdx.x >> 6;
    const int gw = blockIdx.x * (blockDim.x >> 6) + wave;
    const int nw = gridDim.x * (blockDim.x >> 6);
    const float nf = (float)n;

    float accL = 0.f, accV = 0.f;
    for (int r = gw; r < n; r += nw) {
        const int c = L[r];  // wave-uniform
        const float2 v = ((const float2*)(F + (size_t)r * D))[lane];
        const float a0 = S_lds[c * D + 2 * lane];
        const float a1 = S_lds[c * D + 2 * lane + 1];
        const float t0 = Stot[2 * lane];
        const float t1 = Stot[2 * lane + 1];
        float sq    = v.x * v.x + v.y * v.y;
        float dsame = v.x * a0 + v.y * a1;
        float dtot  = v.x * t0 + v.y * t1;
        #pragma unroll
        for (int off = 32; off; off >>= 1) {
            sq    += __shfl_xor(sq, off, 64);
            dsame += __shfl_xor(dsame, off, 64);
            dtot  += __shfl_xor(dtot, off, 64);
        }
        if (lane == 0) {
            const float cntc   = cnt_lds[c];
            const float counts = cntc - 1.f;
            const float same_sum = counts * sq + sq + Q_lds[c] - 2.f * dsame;
            const float diff_sum = (nf - cntc) * sq + (Qtot_s - Q_lds[c])
                                   - 2.f * (dtot - dsame);
            const float loss = same_sum / (counts + EPSF)
                             - diff_sum / (nf - cntc + EPSF) + MF;
            const float valid = counts > 0.5f ? 1.f : 0.f;
            accL += (loss > 0.f ? loss : 0.f) * valid;
            accV += valid;
        }
    }
    if (lane == 0) {
        atomicAdd(&ws[WS_SUM], accL);
        atomicAdd(&ws[WS_SUM + 1], accV);
    }
}

__global__ void final_kernel(const float* __restrict__ ws, float* __restrict__ out) {
    out[0] = ws[WS_SUM] / fmaxf(ws[WS_SUM + 1], 1.f);
}

extern "C" void kernel_launch(void* const* d_in, const int* in_sizes, int n_in,
                              void* d_out, int out_size, void* d_ws, size_t ws_size,
                              hipStream_t stream) {
    const float* F = (const float*)d_in[0];
    const int* L = (const int*)d_in[1];
    float* out = (float*)d_out;
    float* ws = (float*)d_ws;
    const int n = in_sizes[1];  // 8192; in_sizes[0]/n == 128 == D

    hipMemsetAsync(d_ws, 0, WS_FLOATS * sizeof(float), stream);
    agg_kernel<<<64, 128, 0, stream>>>(F, L, ws, n);
    loss_kernel<<<64, 256, 0, stream>>>(F, L, ws, n);
    final_kernel<<<1, 1, 0, stream>>>(ws, out);
}